// Round 4
// baseline (609.181 us; speedup 1.0000x reference)
//
#include <hip/hip_runtime.h>
#include <hip/hip_bf16.h>
#include <cstdint>

// I/O is FP32. Derivation: c=DT=0.1, d=1+DT/EPS=11; layer out = (-u,-v) with
//   V = rhs_v @ Minv + 0.1 * rhsu @ (W Minv),   u_out = 0.1 V W^T - u_in - 0.1 b,
//   Minv = (I - (0.01/11) W^T W)/11  (Neumann, trunc err ~1.5e-6).
// Fused form: V = [vr | rhsu] @ Bcat^T, Bcat = [Minv ; 0.1*(Minv W^T)] (1024x2048),
//   vr = v_in + 10 relu(u_in)  (layer 0: 11*relu(z0)).
// Precision: u fp32 ping-pong; vr/rhsu/V bf16 GEMM operands; logits GEMM uses
// split hi/lo bf16 (3-term).
// R4: true LDS double-buffer K-loop (stage k+1 -> compute k -> ONE barrier):
// global_load_lds latency overlaps the MFMA phase instead of being drained
// immediately (the R3 structure exposed full load latency at 2 blocks/CU).

typedef __bf16 bf16;
typedef __bf16 bf16x4 __attribute__((ext_vector_type(4)));
typedef __bf16 bf16x8 __attribute__((ext_vector_type(8)));
typedef float  f32x4  __attribute__((ext_vector_type(4)));

#define C_DT    0.1f
#define C_DTEPS 10.0f
#define C_DINV  (1.0f/11.0f)
#define C_MSC   (0.01f/121.0f)

__device__ __forceinline__ void async_load16(const bf16* g, bf16* l) {
    __builtin_amdgcn_global_load_lds(
        (__attribute__((address_space(1))) void*)(g),
        (__attribute__((address_space(3))) void*)(l),
        16, 0, 0);
}

// XCD-aware remap for (8,64) grids: per-XCD L2 working set ~ row-panel + B.
__device__ __forceinline__ void remap_block(int& bx, int& by) {
    if (gridDim.y == 64) {
        const int lin  = by * 8 + bx;
        const int xcd  = lin & 7;
        const int slot = lin >> 3;
        by = xcd * 8 + (slot & 7);
        bx = slot >> 3;
    }
}

// ---------------------------------------------------------------------------
// C = A @ B^T (A: MxK ld lda, B: NxK ld ldb, bf16). 128x128 tile, BK=32,
// double-buffered. Epilogues:
// EPI 0 Z0   : t=a+e1[n]; out_f=t; out_b1=11*relu(t); out_b2=t+0.1*e2[n]
// EPI 1 MINV : v=(m==n?1/11:0)-C_MSC*a; out_b1=v; out_b2=v
// EPI 2 SCALE: out_b1 = sgn*a
// EPI 3 V    : out_b1 = a
// EPI 4 UMID : un=0.1a-e0[m*ldf+n]-0.1*e1[n]; out_f=un;
//              out_b1=10*relu(un)-eb[m*N+n]; out_b2=un+0.1*e2[n]
// EPI 5 ULAST: un=...; out_b1=hi(un); out_b2=lo(un)
// ---------------------------------------------------------------------------
template<int EPI>
__global__ __launch_bounds__(256, 2)
void gemm_bt(const bf16* __restrict__ A, const bf16* __restrict__ B,
             float* __restrict__ out_f,
             bf16* __restrict__ out_b1, bf16* __restrict__ out_b2,
             const float* __restrict__ e0, const float* __restrict__ e1,
             const float* __restrict__ e2, const bf16* __restrict__ eb,
             int M, int N, int K, int lda, int ldb,
             int ldf, int ld1, int ld2, float sgn)
{
    __shared__ __attribute__((aligned(16))) char smem[32768];
    bf16* sAe = (bf16*)smem;             // 2 x 4096 elements
    bf16* sBe = (bf16*)(smem + 16384);   // 2 x 4096 elements

    const int t    = threadIdx.x;
    const int wave = t >> 6;
    const int lane = t & 63;
    int bx = blockIdx.x, by = blockIdx.y;
    remap_block(bx, by);
    const long row0 = (long)by * 128;
    const long col0 = (long)bx * 128;
    const int wr = wave >> 1, wc = wave & 1;

    f32x4 acc[4][4];
#pragma unroll
    for (int i = 0; i < 4; i++)
#pragma unroll
        for (int j = 0; j < 4; j++)
            acc[i][j] = f32x4{0.f, 0.f, 0.f, 0.f};

    // Staging (k-chunk XOR swizzle kept from R3; lane-contiguous LDS dest).
    const int  q  = t >> 2;
    const int  gp = ((t & 3) + 4 - ((q + (q >> 2)) & 3)) & 3;
    const bf16* gA = A + (row0 + q) * (long)lda + gp * 8;
    const bf16* gB = B + (col0 + q) * (long)ldb + gp * 8;

    const int l15  = lane & 15;
    const int fch  = ((lane >> 4) + l15 + (l15 >> 2)) & 3;
    const int aoff = (wr * 64 + l15) * 32 + fch * 8;
    const int boff = (wc * 64 + l15) * 32 + fch * 8;

    auto stage = [&](int buf, int k0) {
        bf16* dA = sAe + buf * 4096 + wave * 512;
        bf16* dB = sBe + buf * 4096 + wave * 512;
        async_load16(gA + k0,                     dA);
        async_load16(gA + 64 * (long)lda + k0,    dA + 2048);
        async_load16(gB + k0,                     dB);
        async_load16(gB + 64 * (long)ldb + k0,    dB + 2048);
    };

    const int nIter = K >> 5;
    stage(0, 0);
    __syncthreads();                       // buf0 ready
    for (int k = 0; k < nIter; k++) {
        const int cur = k & 1;
        if (k + 1 < nIter) stage(cur ^ 1, (k + 1) << 5);  // in flight over MFMA

        bf16x8 af[4], bfv[4];
#pragma unroll
        for (int i = 0; i < 4; i++)
            af[i] = *(const bf16x8*)(sAe + cur * 4096 + aoff + i * 16 * 32);
#pragma unroll
        for (int j = 0; j < 4; j++)
            bfv[j] = *(const bf16x8*)(sBe + cur * 4096 + boff + j * 16 * 32);
#pragma unroll
        for (int i = 0; i < 4; i++)
#pragma unroll
            for (int j = 0; j < 4; j++)
                acc[i][j] = __builtin_amdgcn_mfma_f32_16x16x32_bf16(
                    af[i], bfv[j], acc[i][j], 0, 0, 0);

        __syncthreads();   // drains next-tile loads; frees cur for k+2 staging
    }

    // Coalesced epilogue via wave-private LDS transpose (reuses smem).
    float* epi = (float*)smem + wave * 1024;
    const int wbase = (lane >> 4) * 256 + (l15 >> 2) * 4 + (l15 & 3);

#pragma unroll
    for (int i = 0; i < 4; i++) {
#pragma unroll
        for (int j = 0; j < 4; j++)
#pragma unroll
            for (int r = 0; r < 4; r++)
                epi[wbase + r * 64 + 16 * j] = acc[i][j][r];

#pragma unroll
        for (int qq = 0; qq < 4; qq++) {
            const f32x4 a4 = ((const f32x4*)epi)[qq * 64 + lane];
            const long m = row0 + wr * 64 + i * 16 + qq * 4 + (lane >> 4);
            const long n = col0 + wc * 64 + 4 * l15;

            if (EPI == 0) {
                const f32x4 b1 = *(const f32x4*)(e1 + n);
                const f32x4 b2 = *(const f32x4*)(e2 + n);
                f32x4 tv; bf16x4 rv, hv;
#pragma unroll
                for (int e = 0; e < 4; e++) {
                    tv[e] = a4[e] + b1[e];
                    rv[e] = (bf16)(11.f * fmaxf(tv[e], 0.f));
                    hv[e] = (bf16)(tv[e] + C_DT * b2[e]);
                }
                *(f32x4*)(out_f + m * (long)ldf + n)    = tv;
                *(bf16x4*)(out_b1 + m * (long)ld1 + n)  = rv;
                *(bf16x4*)(out_b2 + m * (long)ld2 + n)  = hv;
            } else if (EPI == 1) {
                bf16x4 ov;
#pragma unroll
                for (int e = 0; e < 4; e++)
                    ov[e] = (bf16)(((m == n + e) ? C_DINV : 0.f) - C_MSC * a4[e]);
                *(bf16x4*)(out_b1 + m * (long)ld1 + n) = ov;
                *(bf16x4*)(out_b2 + m * (long)ld2 + n) = ov;
            } else if (EPI == 2) {
                bf16x4 ov;
#pragma unroll
                for (int e = 0; e < 4; e++) ov[e] = (bf16)(sgn * a4[e]);
                *(bf16x4*)(out_b1 + m * (long)ld1 + n) = ov;
            } else if (EPI == 3) {
                bf16x4 ov;
#pragma unroll
                for (int e = 0; e < 4; e++) ov[e] = (bf16)a4[e];
                *(bf16x4*)(out_b1 + m * (long)ld1 + n) = ov;
            } else if (EPI == 4) {
                const f32x4  u0 = *(const f32x4*)(e0 + m * (long)ldf + n);
                const f32x4  b1 = *(const f32x4*)(e1 + n);
                const f32x4  b2 = *(const f32x4*)(e2 + n);
                const bf16x4 vv = *(const bf16x4*)(eb + m * (long)N + n);
                f32x4 un; bf16x4 rv, hv;
#pragma unroll
                for (int e = 0; e < 4; e++) {
                    un[e] = C_DT * a4[e] - u0[e] - C_DT * b1[e];
                    rv[e] = (bf16)(C_DTEPS * fmaxf(un[e], 0.f) - (float)vv[e]);
                    hv[e] = (bf16)(un[e] + C_DT * b2[e]);
                }
                *(f32x4*)(out_f + m * (long)ldf + n)    = un;
                *(bf16x4*)(out_b1 + m * (long)ld1 + n)  = rv;
                *(bf16x4*)(out_b2 + m * (long)ld2 + n)  = hv;
            } else {
                const f32x4 u0 = *(const f32x4*)(e0 + m * (long)ldf + n);
                const f32x4 b1 = *(const f32x4*)(e1 + n);
                bf16x4 hv, lv;
#pragma unroll
                for (int e = 0; e < 4; e++) {
                    float un = C_DT * a4[e] - u0[e] - C_DT * b1[e];
                    bf16 h = (bf16)un;
                    hv[e] = h;
                    lv[e] = (bf16)(un - (float)h);
                }
                *(bf16x4*)(out_b1 + m * (long)ld1 + n) = hv;
                *(bf16x4*)(out_b2 + m * (long)ld2 + n) = lv;
            }
        }
    }
}

// logits = (Ah+Al)@(Bh+Bl)^T + bias (3-term), fp32 out, double-buffered.
__global__ __launch_bounds__(256, 2)
void gemm_split(const bf16* __restrict__ Ah, const bf16* __restrict__ Al,
                const bf16* __restrict__ Bh, const bf16* __restrict__ Bl,
                float* __restrict__ out, const float* __restrict__ bias,
                int M, int N, int K, int blim)
{
    __shared__ __attribute__((aligned(16))) char smem[65536];
    bf16* sAh = (bf16*)smem;
    bf16* sAl = (bf16*)(smem + 16384);
    bf16* sBh = (bf16*)(smem + 32768);
    bf16* sBl = (bf16*)(smem + 49152);

    const int t    = threadIdx.x;
    const int wave = t >> 6;
    const int lane = t & 63;
    int bx = blockIdx.x, by = blockIdx.y;
    remap_block(bx, by);
    const long row0 = (long)by * 128;
    const long col0 = (long)bx * 128;
    const int wr = wave >> 1, wc = wave & 1;

    f32x4 acc[4][4];
#pragma unroll
    for (int i = 0; i < 4; i++)
#pragma unroll
        for (int j = 0; j < 4; j++)
            acc[i][j] = f32x4{0.f, 0.f, 0.f, 0.f};

    const int  q  = t >> 2;
    const int  gp = ((t & 3) + 4 - ((q + (q >> 2)) & 3)) & 3;
    const long gao = (row0 + q) * (long)K + gp * 8;
    const long gbo = (col0 + q) * (long)K + gp * 8;

    const int l15  = lane & 15;
    const int fch  = ((lane >> 4) + l15 + (l15 >> 2)) & 3;
    const int aoff = (wr * 64 + l15) * 32 + fch * 8;
    const int boff = (wc * 64 + l15) * 32 + fch * 8;

    auto stage = [&](int buf, int k0) {
        const int d = buf * 4096 + wave * 512;
        async_load16(Ah + gao + k0,                 sAh + d);
        async_load16(Ah + gao + 64 * (long)K + k0,  sAh + d + 2048);
        async_load16(Al + gao + k0,                 sAl + d);
        async_load16(Al + gao + 64 * (long)K + k0,  sAl + d + 2048);
        async_load16(Bh + gbo + k0,                 sBh + d);
        async_load16(Bh + gbo + 64 * (long)K + k0,  sBh + d + 2048);
        async_load16(Bl + gbo + k0,                 sBl + d);
        async_load16(Bl + gbo + 64 * (long)K + k0,  sBl + d + 2048);
    };

    const int nIter = K >> 5;
    stage(0, 0);
    __syncthreads();
    for (int k = 0; k < nIter; k++) {
        const int cur = k & 1;
        if (k + 1 < nIter) stage(cur ^ 1, (k + 1) << 5);

        bf16x8 ah[4], al[4], bh[4], bl[4];
#pragma unroll
        for (int i = 0; i < 4; i++) {
            ah[i] = *(const bf16x8*)(sAh + cur * 4096 + aoff + i * 16 * 32);
            al[i] = *(const bf16x8*)(sAl + cur * 4096 + aoff + i * 16 * 32);
        }
#pragma unroll
        for (int j = 0; j < 4; j++) {
            bh[j] = *(const bf16x8*)(sBh + cur * 4096 + boff + j * 16 * 32);
            bl[j] = *(const bf16x8*)(sBl + cur * 4096 + boff + j * 16 * 32);
        }
#pragma unroll
        for (int i = 0; i < 4; i++)
#pragma unroll
            for (int j = 0; j < 4; j++) {
                acc[i][j] = __builtin_amdgcn_mfma_f32_16x16x32_bf16(
                    ah[i], bh[j], acc[i][j], 0, 0, 0);
                acc[i][j] = __builtin_amdgcn_mfma_f32_16x16x32_bf16(
                    ah[i], bl[j], acc[i][j], 0, 0, 0);
                acc[i][j] = __builtin_amdgcn_mfma_f32_16x16x32_bf16(
                    al[i], bh[j], acc[i][j], 0, 0, 0);
            }
        __syncthreads();
    }

    float* epi = (float*)smem + wave * 1024;
    const int wbase = (lane >> 4) * 256 + (l15 >> 2) * 4 + (l15 & 3);

#pragma unroll
    for (int i = 0; i < 4; i++) {
#pragma unroll
        for (int j = 0; j < 4; j++)
#pragma unroll
            for (int r = 0; r < 4; r++)
                epi[wbase + r * 64 + 16 * j] = acc[i][j][r];

#pragma unroll
        for (int qq = 0; qq < 4; qq++) {
            f32x4 a4 = ((const f32x4*)epi)[qq * 64 + lane];
            const long m = row0 + wr * 64 + i * 16 + qq * 4 + (lane >> 4);
            const long n = col0 + wc * 64 + 4 * l15;
            f32x4 bv = f32x4{0.f, 0.f, 0.f, 0.f};
            if (n < blim) bv = *(const f32x4*)(bias + n);
#pragma unroll
            for (int e = 0; e < 4; e++) a4[e] += bv[e];
            *(f32x4*)(out + m * (long)N + n) = a4;
        }
    }
}

__global__ void conv_f2b_v4(const float* __restrict__ in, bf16* __restrict__ out)
{
    const long i4 = (long)blockIdx.x * 256 + threadIdx.x;
    const f32x4 v = ((const f32x4*)in)[i4];
    bf16x4 o;
#pragma unroll
    for (int e = 0; e < 4; e++) o[e] = (bf16)v[e];
    ((bf16x4*)out)[i4] = o;
}

__global__ void prep_w(const float* __restrict__ W, bf16* __restrict__ Wb,
                       bf16* __restrict__ Wtb)
{
    __shared__ float tile[32][33];
    const int bx = blockIdx.x * 32, by = blockIdx.y * 32;
    const int tx = threadIdx.x & 31, ty = threadIdx.x >> 5;
#pragma unroll
    for (int i = 0; i < 32; i += 8) {
        float v = W[(long)(by + ty + i) * 1024 + bx + tx];
        tile[ty + i][tx] = v;
        Wb[(long)(by + ty + i) * 1024 + bx + tx] = (bf16)v;
    }
    __syncthreads();
#pragma unroll
    for (int i = 0; i < 32; i += 8)
        Wtb[(long)(bx + ty + i) * 1024 + by + tx] = (bf16)tile[tx][ty + i];
}

__global__ void prep_wout(const float* __restrict__ w, bf16* __restrict__ wh,
                          bf16* __restrict__ wl)
{
    const long i4   = (long)blockIdx.x * 256 + threadIdx.x;
    const long base = i4 * 4;
    const int  nrow = (int)(base >> 10);
    bf16x4 h, l;
    if (nrow < 1000) {
        const f32x4 v = ((const f32x4*)w)[i4];
#pragma unroll
        for (int e = 0; e < 4; e++) {
            bf16 hh = (bf16)v[e];
            h[e] = hh;
            l[e] = (bf16)(v[e] - (float)hh);
        }
    } else {
#pragma unroll
        for (int e = 0; e < 4; e++) { h[e] = (bf16)0.f; l[e] = (bf16)0.f; }
    }
    ((bf16x4*)wh)[i4] = h;
    ((bf16x4*)wl)[i4] = l;
}

__global__ __launch_bounds__(256)
void softmax_rows(const float* __restrict__ logits, float* __restrict__ out)
{
    const int row = blockIdx.x;
    const float* lp = logits + (long)row * 1024;
    const int t = threadIdx.x;
    float v[4];
    float mx = -1e30f;
#pragma unroll
    for (int i = 0; i < 4; i++) {
        const int c = t + i * 256;
        v[i] = (c < 1000) ? lp[c] : -1e30f;
        mx = fmaxf(mx, v[i]);
    }
#pragma unroll
    for (int off = 32; off; off >>= 1)
        mx = fmaxf(mx, __shfl_xor(mx, off));
    __shared__ float sm[4], ss[4];
    const int wave = t >> 6;
    if ((t & 63) == 0) sm[wave] = mx;
    __syncthreads();
    mx = fmaxf(fmaxf(sm[0], sm[1]), fmaxf(sm[2], sm[3]));
    float sum = 0.f;
#pragma unroll
    for (int i = 0; i < 4; i++) {
        v[i] = __expf(v[i] - mx);
        sum += v[i];
    }
#pragma unroll
    for (int off = 32; off; off >>= 1)
        sum += __shfl_xor(sum, off);
    if ((t & 63) == 0) ss[wave] = sum;
    __syncthreads();
    const float inv = 1.f / (ss[0] + ss[1] + ss[2] + ss[3]);
#pragma unroll
    for (int i = 0; i < 4; i++) {
        const int c = t + i * 256;
        if (c < 1000) out[(long)row * 1000 + c] = v[i] * inv;
    }
}

extern "C" void kernel_launch(void* const* d_in, const int* in_sizes, int n_in,
                              void* d_out, int out_size, void* d_ws, size_t ws_size,
                              hipStream_t stream)
{
    const float* x     = (const float*)d_in[0];
    const float* W_in  = (const float*)d_in[1];
    const float* b_in  = (const float*)d_in[2];
    const float* Ws[3] = {(const float*)d_in[3], (const float*)d_in[5], (const float*)d_in[7]};
    const float* bs[3] = {(const float*)d_in[4], (const float*)d_in[6], (const float*)d_in[8]};
    const float* W_out = (const float*)d_in[9];
    const float* b_out = (const float*)d_in[10];
    float* out = (float*)d_out;

    char* ws = (char*)d_ws;
    const size_t MB = 1u << 20;
    bf16*  xb    = (bf16*)(ws);              // 32 MB  bf16(x) 8192x2048
    bf16*  Winb  = (bf16*)(ws +  32 * MB);   //  4 MB
    bf16*  Wouth = (bf16*)(ws +  36 * MB);   //  2 MB
    bf16*  Woutl = (bf16*)(ws +  38 * MB);   //  2 MB
    bf16*  Wbf   = (bf16*)(ws +  40 * MB);   //  2 MB
    bf16*  Wtbf  = (bf16*)(ws +  42 * MB);   //  2 MB
    bf16*  Minvb = (bf16*)(ws +  44 * MB);   //  2 MB
    bf16*  Bcat  = (bf16*)(ws +  46 * MB);   //  4 MB  [Minv | 0.1*Minv@W^T] 1024x2048
    float* u_a   = (float*)(ws +  50 * MB);  // 32 MB
    float* u_b   = (float*)(ws +  82 * MB);  // 32 MB
    bf16*  AC    = (bf16*)(ws + 114 * MB);   // 32 MB  [vr | rhsu] 8192x2048
    bf16*  vb    = (bf16*)(ws + 146 * MB);   // 16 MB  V
    bf16*  zh    = AC;                       // last layer: z hi (8192x1024)
    bf16*  zl    = AC + 8192L * 1024;        //            z lo
    float* logits = u_b;                     // free at l=2 (uin=u_a)

    const dim3 blk(256);
    const dim3 gBig(8, 64);
    const dim3 gSm(8, 8);
    const dim3 gT(32, 32);

    conv_f2b_v4<<<16384, blk, 0, stream>>>(x, xb);
    conv_f2b_v4<<<2048,  blk, 0, stream>>>(W_in, Winb);
    prep_wout<<<1024, blk, 0, stream>>>(W_out, Wouth, Woutl);

    // z0: u_a = z0 (fp32), AC = [11*relu(z0) | z0 + 0.1*b1]
    gemm_bt<0><<<gBig, blk, 0, stream>>>(xb, Winb, u_a, AC, AC + 1024,
                                         nullptr, b_in, bs[0], nullptr,
                                         8192, 1024, 2048, 2048, 2048,
                                         1024, 2048, 2048, 1.f);

    float* uin[3]  = {u_a, u_b, u_a};
    float* uout[3] = {u_b, u_a, nullptr};
    for (int l = 0; l < 3; l++) {
        prep_w<<<gT, blk, 0, stream>>>(Ws[l], Wbf, Wtbf);
        // Minv = (I - C_MSC*W^T W)/.. -> Minvb (ld 1024) and Bcat[:, :1024]
        gemm_bt<1><<<gSm, blk, 0, stream>>>(Wtbf, Wtbf, nullptr, Minvb, Bcat,
                                            nullptr, nullptr, nullptr, nullptr,
                                            1024, 1024, 1024, 1024, 1024,
                                            0, 1024, 2048, 1.f);
        // Bcat[:, 1024:] = 0.1 * Minv @ W^T
        gemm_bt<2><<<gSm, blk, 0, stream>>>(Minvb, Wbf, nullptr, Bcat + 1024, nullptr,
                                            nullptr, nullptr, nullptr, nullptr,
                                            1024, 1024, 1024, 1024, 1024,
                                            0, 2048, 0, C_DT);
        // V = AC @ Bcat^T  (K=2048)
        gemm_bt<3><<<gBig, blk, 0, stream>>>(AC, Bcat, nullptr, vb, nullptr,
                                             nullptr, nullptr, nullptr, nullptr,
                                             8192, 1024, 2048, 2048, 2048,
                                             0, 1024, 0, 1.f);
        // u_out = 0.1*V@W^T - u_in - 0.1*b; epilogue builds next AC (or z split)
        if (l < 2) {
            gemm_bt<4><<<gBig, blk, 0, stream>>>(vb, Wbf, uout[l], AC, AC + 1024,
                                                 uin[l], bs[l], bs[l + 1], vb,
                                                 8192, 1024, 1024, 1024, 1024,
                                                 1024, 2048, 2048, 1.f);
        } else {
            gemm_bt<5><<<gBig, blk, 0, stream>>>(vb, Wbf, nullptr, zh, zl,
                                                 uin[l], bs[l], nullptr, nullptr,
                                                 8192, 1024, 1024, 1024, 1024,
                                                 1024, 1024, 1024, 1.f);
        }
    }

    gemm_split<<<gBig, blk, 0, stream>>>(zh, zl, Wouth, Woutl, logits, b_out,
                                         8192, 1024, 1024, 1000);
    softmax_rows<<<8192, blk, 0, stream>>>(logits, out);
}

// Round 5
// 529.106 us; speedup vs baseline: 1.1513x; 1.1513x over previous
//
#include <hip/hip_runtime.h>
#include <hip/hip_bf16.h>
#include <cstdint>

// I/O is FP32. Derivation: c=DT=0.1, d=1+DT/EPS=11; layer out = (-u,-v) with
//   V = [vr | rhsu] @ Bcat^T, Bcat = [Minv ; 0.1*(Minv W^T)] (1024x2048),
//   vr = v_in + 10 relu(u_in)  (layer 0: 11*relu(z0)),
//   u_out = 0.1 V W^T - u_in - 0.1 b,
//   Minv = (I - (0.01/11) W^T W)/11  (Neumann, trunc err ~1.5e-6).
// Precision: u fp32 ping-pong; vr/rhsu/V bf16 GEMM operands; logits GEMM uses
// split hi/lo bf16 (3-term).
// R5: all per-layer weight products batched across layers via blockIdx.z
// (9 small dispatches -> 3, 64 -> 192 blocks each); z0 runs first so the dead
// xb region holds the weight products; 25 -> 11 dispatches total.

typedef __bf16 bf16;
typedef __bf16 bf16x4 __attribute__((ext_vector_type(4)));
typedef __bf16 bf16x8 __attribute__((ext_vector_type(8)));
typedef float  f32x4  __attribute__((ext_vector_type(4)));

#define C_DT    0.1f
#define C_DTEPS 10.0f
#define C_DINV  (1.0f/11.0f)
#define C_MSC   (0.01f/121.0f)

__device__ __forceinline__ void async_load16(const bf16* g, bf16* l) {
    __builtin_amdgcn_global_load_lds(
        (__attribute__((address_space(1))) void*)(g),
        (__attribute__((address_space(3))) void*)(l),
        16, 0, 0);
}

// XCD-aware remap for (8,64) grids: per-XCD L2 working set ~ row-panel + B.
__device__ __forceinline__ void remap_block(int& bx, int& by) {
    if (gridDim.y == 64) {
        const int lin  = by * 8 + bx;
        const int xcd  = lin & 7;
        const int slot = lin >> 3;
        by = xcd * 8 + (slot & 7);
        bx = slot >> 3;
    }
}

// ---------------------------------------------------------------------------
// C = A @ B^T (A: MxK ld lda, B: NxK ld ldb, bf16). 128x128 tile, BK=32,
// double-buffered. Batched over blockIdx.z with element strides zsA/zsB/zs1/zs2.
// EPI 0 Z0   : t=a+e1[n]; out_f=t; out_b1=11*relu(t); out_b2=t+0.1*e2[n]
// EPI 1 MINV : v=(m==n?1/11:0)-C_MSC*a; out_b1=v; out_b2=v
// EPI 2 SCALE: out_b1 = sgn*a
// EPI 3 V    : out_b1 = a
// EPI 4 UMID : un=0.1a-e0[m*ldf+n]-0.1*e1[n]; out_f=un;
//              out_b1=10*relu(un)-eb[m*N+n]; out_b2=un+0.1*e2[n]
// EPI 5 ULAST: un=...; out_b1=hi(un); out_b2=lo(un)
// ---------------------------------------------------------------------------
template<int EPI>
__global__ __launch_bounds__(256, 2)
void gemm_bt(const bf16* __restrict__ A, const bf16* __restrict__ B,
             float* __restrict__ out_f,
             bf16* __restrict__ out_b1, bf16* __restrict__ out_b2,
             const float* __restrict__ e0, const float* __restrict__ e1,
             const float* __restrict__ e2, const bf16* __restrict__ eb,
             int M, int N, int K, int lda, int ldb,
             int ldf, int ld1, int ld2, float sgn,
             long zsA, long zsB, long zs1, long zs2)
{
    __shared__ __attribute__((aligned(16))) char smem[32768];
    bf16* sAe = (bf16*)smem;             // 2 x 4096 elements
    bf16* sBe = (bf16*)(smem + 16384);   // 2 x 4096 elements

    const int t    = threadIdx.x;
    const int wave = t >> 6;
    const int lane = t & 63;
    int bx = blockIdx.x, by = blockIdx.y;
    remap_block(bx, by);
    const long zb = blockIdx.z;
    A += zb * zsA;
    B += zb * zsB;
    if (out_b1) out_b1 += zb * zs1;
    if (out_b2) out_b2 += zb * zs2;

    const long row0 = (long)by * 128;
    const long col0 = (long)bx * 128;
    const int wr = wave >> 1, wc = wave & 1;

    f32x4 acc[4][4];
#pragma unroll
    for (int i = 0; i < 4; i++)
#pragma unroll
        for (int j = 0; j < 4; j++)
            acc[i][j] = f32x4{0.f, 0.f, 0.f, 0.f};

    // Staging (k-chunk XOR swizzle; lane-contiguous LDS dest).
    const int  q  = t >> 2;
    const int  gp = ((t & 3) + 4 - ((q + (q >> 2)) & 3)) & 3;
    const bf16* gA = A + (row0 + q) * (long)lda + gp * 8;
    const bf16* gB = B + (col0 + q) * (long)ldb + gp * 8;

    const int l15  = lane & 15;
    const int fch  = ((lane >> 4) + l15 + (l15 >> 2)) & 3;
    const int aoff = (wr * 64 + l15) * 32 + fch * 8;
    const int boff = (wc * 64 + l15) * 32 + fch * 8;

    auto stage = [&](int buf, int k0) {
        bf16* dA = sAe + buf * 4096 + wave * 512;
        bf16* dB = sBe + buf * 4096 + wave * 512;
        async_load16(gA + k0,                     dA);
        async_load16(gA + 64 * (long)lda + k0,    dA + 2048);
        async_load16(gB + k0,                     dB);
        async_load16(gB + 64 * (long)ldb + k0,    dB + 2048);
    };

    const int nIter = K >> 5;
    stage(0, 0);
    __syncthreads();
    for (int k = 0; k < nIter; k++) {
        const int cur = k & 1;
        if (k + 1 < nIter) stage(cur ^ 1, (k + 1) << 5);

        bf16x8 af[4], bfv[4];
#pragma unroll
        for (int i = 0; i < 4; i++)
            af[i] = *(const bf16x8*)(sAe + cur * 4096 + aoff + i * 16 * 32);
#pragma unroll
        for (int j = 0; j < 4; j++)
            bfv[j] = *(const bf16x8*)(sBe + cur * 4096 + boff + j * 16 * 32);
#pragma unroll
        for (int i = 0; i < 4; i++)
#pragma unroll
            for (int j = 0; j < 4; j++)
                acc[i][j] = __builtin_amdgcn_mfma_f32_16x16x32_bf16(
                    af[i], bfv[j], acc[i][j], 0, 0, 0);

        __syncthreads();
    }

    // Coalesced epilogue via wave-private LDS transpose (reuses smem).
    float* epi = (float*)smem + wave * 1024;
    const int wbase = (lane >> 4) * 256 + (l15 >> 2) * 4 + (l15 & 3);

#pragma unroll
    for (int i = 0; i < 4; i++) {
#pragma unroll
        for (int j = 0; j < 4; j++)
#pragma unroll
            for (int r = 0; r < 4; r++)
                epi[wbase + r * 64 + 16 * j] = acc[i][j][r];

#pragma unroll
        for (int qq = 0; qq < 4; qq++) {
            const f32x4 a4 = ((const f32x4*)epi)[qq * 64 + lane];
            const long m = row0 + wr * 64 + i * 16 + qq * 4 + (lane >> 4);
            const long n = col0 + wc * 64 + 4 * l15;

            if (EPI == 0) {
                const f32x4 b1 = *(const f32x4*)(e1 + n);
                const f32x4 b2 = *(const f32x4*)(e2 + n);
                f32x4 tv; bf16x4 rv, hv;
#pragma unroll
                for (int e = 0; e < 4; e++) {
                    tv[e] = a4[e] + b1[e];
                    rv[e] = (bf16)(11.f * fmaxf(tv[e], 0.f));
                    hv[e] = (bf16)(tv[e] + C_DT * b2[e]);
                }
                *(f32x4*)(out_f + m * (long)ldf + n)    = tv;
                *(bf16x4*)(out_b1 + m * (long)ld1 + n)  = rv;
                *(bf16x4*)(out_b2 + m * (long)ld2 + n)  = hv;
            } else if (EPI == 1) {
                bf16x4 ov;
#pragma unroll
                for (int e = 0; e < 4; e++)
                    ov[e] = (bf16)(((m == n + e) ? C_DINV : 0.f) - C_MSC * a4[e]);
                *(bf16x4*)(out_b1 + m * (long)ld1 + n) = ov;
                *(bf16x4*)(out_b2 + m * (long)ld2 + n) = ov;
            } else if (EPI == 2) {
                bf16x4 ov;
#pragma unroll
                for (int e = 0; e < 4; e++) ov[e] = (bf16)(sgn * a4[e]);
                *(bf16x4*)(out_b1 + m * (long)ld1 + n) = ov;
            } else if (EPI == 3) {
                bf16x4 ov;
#pragma unroll
                for (int e = 0; e < 4; e++) ov[e] = (bf16)a4[e];
                *(bf16x4*)(out_b1 + m * (long)ld1 + n) = ov;
            } else if (EPI == 4) {
                const f32x4  u0 = *(const f32x4*)(e0 + m * (long)ldf + n);
                const f32x4  b1 = *(const f32x4*)(e1 + n);
                const f32x4  b2 = *(const f32x4*)(e2 + n);
                const bf16x4 vv = *(const bf16x4*)(eb + m * (long)N + n);
                f32x4 un; bf16x4 rv, hv;
#pragma unroll
                for (int e = 0; e < 4; e++) {
                    un[e] = C_DT * a4[e] - u0[e] - C_DT * b1[e];
                    rv[e] = (bf16)(C_DTEPS * fmaxf(un[e], 0.f) - (float)vv[e]);
                    hv[e] = (bf16)(un[e] + C_DT * b2[e]);
                }
                *(f32x4*)(out_f + m * (long)ldf + n)    = un;
                *(bf16x4*)(out_b1 + m * (long)ld1 + n)  = rv;
                *(bf16x4*)(out_b2 + m * (long)ld2 + n)  = hv;
            } else {
                const f32x4 u0 = *(const f32x4*)(e0 + m * (long)ldf + n);
                const f32x4 b1 = *(const f32x4*)(e1 + n);
                bf16x4 hv, lv;
#pragma unroll
                for (int e = 0; e < 4; e++) {
                    float un = C_DT * a4[e] - u0[e] - C_DT * b1[e];
                    bf16 h = (bf16)un;
                    hv[e] = h;
                    lv[e] = (bf16)(un - (float)h);
                }
                *(bf16x4*)(out_b1 + m * (long)ld1 + n) = hv;
                *(bf16x4*)(out_b2 + m * (long)ld2 + n) = lv;
            }
        }
    }
}

// logits = (Ah+Al)@(Bh+Bl)^T + bias (3-term), fp32 out, double-buffered.
__global__ __launch_bounds__(256, 2)
void gemm_split(const bf16* __restrict__ Ah, const bf16* __restrict__ Al,
                const bf16* __restrict__ Bh, const bf16* __restrict__ Bl,
                float* __restrict__ out, const float* __restrict__ bias,
                int M, int N, int K, int blim)
{
    __shared__ __attribute__((aligned(16))) char smem[65536];
    bf16* sAh = (bf16*)smem;
    bf16* sAl = (bf16*)(smem + 16384);
    bf16* sBh = (bf16*)(smem + 32768);
    bf16* sBl = (bf16*)(smem + 49152);

    const int t    = threadIdx.x;
    const int wave = t >> 6;
    const int lane = t & 63;
    int bx = blockIdx.x, by = blockIdx.y;
    remap_block(bx, by);
    const long row0 = (long)by * 128;
    const long col0 = (long)bx * 128;
    const int wr = wave >> 1, wc = wave & 1;

    f32x4 acc[4][4];
#pragma unroll
    for (int i = 0; i < 4; i++)
#pragma unroll
        for (int j = 0; j < 4; j++)
            acc[i][j] = f32x4{0.f, 0.f, 0.f, 0.f};

    const int  q  = t >> 2;
    const int  gp = ((t & 3) + 4 - ((q + (q >> 2)) & 3)) & 3;
    const long gao = (row0 + q) * (long)K + gp * 8;
    const long gbo = (col0 + q) * (long)K + gp * 8;

    const int l15  = lane & 15;
    const int fch  = ((lane >> 4) + l15 + (l15 >> 2)) & 3;
    const int aoff = (wr * 64 + l15) * 32 + fch * 8;
    const int boff = (wc * 64 + l15) * 32 + fch * 8;

    auto stage = [&](int buf, int k0) {
        const int d = buf * 4096 + wave * 512;
        async_load16(Ah + gao + k0,                 sAh + d);
        async_load16(Ah + gao + 64 * (long)K + k0,  sAh + d + 2048);
        async_load16(Al + gao + k0,                 sAl + d);
        async_load16(Al + gao + 64 * (long)K + k0,  sAl + d + 2048);
        async_load16(Bh + gbo + k0,                 sBh + d);
        async_load16(Bh + gbo + 64 * (long)K + k0,  sBh + d + 2048);
        async_load16(Bl + gbo + k0,                 sBl + d);
        async_load16(Bl + gbo + 64 * (long)K + k0,  sBl + d + 2048);
    };

    const int nIter = K >> 5;
    stage(0, 0);
    __syncthreads();
    for (int k = 0; k < nIter; k++) {
        const int cur = k & 1;
        if (k + 1 < nIter) stage(cur ^ 1, (k + 1) << 5);

        bf16x8 ah[4], al[4], bh[4], bl[4];
#pragma unroll
        for (int i = 0; i < 4; i++) {
            ah[i] = *(const bf16x8*)(sAh + cur * 4096 + aoff + i * 16 * 32);
            al[i] = *(const bf16x8*)(sAl + cur * 4096 + aoff + i * 16 * 32);
        }
#pragma unroll
        for (int j = 0; j < 4; j++) {
            bh[j] = *(const bf16x8*)(sBh + cur * 4096 + boff + j * 16 * 32);
            bl[j] = *(const bf16x8*)(sBl + cur * 4096 + boff + j * 16 * 32);
        }
#pragma unroll
        for (int i = 0; i < 4; i++)
#pragma unroll
            for (int j = 0; j < 4; j++) {
                acc[i][j] = __builtin_amdgcn_mfma_f32_16x16x32_bf16(
                    ah[i], bh[j], acc[i][j], 0, 0, 0);
                acc[i][j] = __builtin_amdgcn_mfma_f32_16x16x32_bf16(
                    ah[i], bl[j], acc[i][j], 0, 0, 0);
                acc[i][j] = __builtin_amdgcn_mfma_f32_16x16x32_bf16(
                    al[i], bh[j], acc[i][j], 0, 0, 0);
            }
        __syncthreads();
    }

    float* epi = (float*)smem + wave * 1024;
    const int wbase = (lane >> 4) * 256 + (l15 >> 2) * 4 + (l15 & 3);

#pragma unroll
    for (int i = 0; i < 4; i++) {
#pragma unroll
        for (int j = 0; j < 4; j++)
#pragma unroll
            for (int r = 0; r < 4; r++)
                epi[wbase + r * 64 + 16 * j] = acc[i][j][r];

#pragma unroll
        for (int qq = 0; qq < 4; qq++) {
            f32x4 a4 = ((const f32x4*)epi)[qq * 64 + lane];
            const long m = row0 + wr * 64 + i * 16 + qq * 4 + (lane >> 4);
            const long n = col0 + wc * 64 + 4 * l15;
            f32x4 bv = f32x4{0.f, 0.f, 0.f, 0.f};
            if (n < blim) bv = *(const f32x4*)(bias + n);
#pragma unroll
            for (int e = 0; e < 4; e++) a4[e] += bv[e];
            *(f32x4*)(out + m * (long)N + n) = a4;
        }
    }
}

// fp32 -> bf16 for x (16384 blocks) and W_in (2048 blocks) in one dispatch
__global__ void conv_xw(const float* __restrict__ x, bf16* __restrict__ xb,
                        const float* __restrict__ w, bf16* __restrict__ wb)
{
    const long bid = blockIdx.x;
    const float* in;
    bf16* outp;
    long i4;
    if (bid < 16384) { in = x; outp = xb; i4 = bid * 256 + threadIdx.x; }
    else             { in = w; outp = wb; i4 = (bid - 16384) * 256 + threadIdx.x; }
    const f32x4 v = ((const f32x4*)in)[i4];
    bf16x4 o;
#pragma unroll
    for (int e = 0; e < 4; e++) o[e] = (bf16)v[e];
    ((bf16x4*)outp)[i4] = o;
}

// Batched over blockIdx.z: W[z] (1024x1024 fp32) -> Wb[z] bf16, Wtb[z] = bf16(W^T)
__global__ void prep_w3(const float* __restrict__ w0, const float* __restrict__ w1,
                        const float* __restrict__ w2, bf16* __restrict__ Wb,
                        bf16* __restrict__ Wtb)
{
    __shared__ float tile[32][33];
    const int z = blockIdx.z;
    const float* W = (z == 0) ? w0 : (z == 1) ? w1 : w2;
    const long zo = (long)z * 1024 * 1024;
    const int bx = blockIdx.x * 32, by = blockIdx.y * 32;
    const int tx = threadIdx.x & 31, ty = threadIdx.x >> 5;
#pragma unroll
    for (int i = 0; i < 32; i += 8) {
        float v = W[(long)(by + ty + i) * 1024 + bx + tx];
        tile[ty + i][tx] = v;
        Wb[zo + (long)(by + ty + i) * 1024 + bx + tx] = (bf16)v;
    }
    __syncthreads();
#pragma unroll
    for (int i = 0; i < 32; i += 8)
        Wtb[zo + (long)(bx + ty + i) * 1024 + by + tx] = (bf16)tile[tx][ty + i];
}

__global__ void prep_wout(const float* __restrict__ w, bf16* __restrict__ wh,
                          bf16* __restrict__ wl)
{
    const long i4   = (long)blockIdx.x * 256 + threadIdx.x;
    const long base = i4 * 4;
    const int  nrow = (int)(base >> 10);
    bf16x4 h, l;
    if (nrow < 1000) {
        const f32x4 v = ((const f32x4*)w)[i4];
#pragma unroll
        for (int e = 0; e < 4; e++) {
            bf16 hh = (bf16)v[e];
            h[e] = hh;
            l[e] = (bf16)(v[e] - (float)hh);
        }
    } else {
#pragma unroll
        for (int e = 0; e < 4; e++) { h[e] = (bf16)0.f; l[e] = (bf16)0.f; }
    }
    ((bf16x4*)wh)[i4] = h;
    ((bf16x4*)wl)[i4] = l;
}

__global__ __launch_bounds__(256)
void softmax_rows(const float* __restrict__ logits, float* __restrict__ out)
{
    const int row = blockIdx.x;
    const float* lp = logits + (long)row * 1024;
    const int t = threadIdx.x;
    float v[4];
    float mx = -1e30f;
#pragma unroll
    for (int i = 0; i < 4; i++) {
        const int c = t + i * 256;
        v[i] = (c < 1000) ? lp[c] : -1e30f;
        mx = fmaxf(mx, v[i]);
    }
#pragma unroll
    for (int off = 32; off; off >>= 1)
        mx = fmaxf(mx, __shfl_xor(mx, off));
    __shared__ float sm[4], ss[4];
    const int wave = t >> 6;
    if ((t & 63) == 0) sm[wave] = mx;
    __syncthreads();
    mx = fmaxf(fmaxf(sm[0], sm[1]), fmaxf(sm[2], sm[3]));
    float sum = 0.f;
#pragma unroll
    for (int i = 0; i < 4; i++) {
        v[i] = __expf(v[i] - mx);
        sum += v[i];
    }
#pragma unroll
    for (int off = 32; off; off >>= 1)
        sum += __shfl_xor(sum, off);
    if ((t & 63) == 0) ss[wave] = sum;
    __syncthreads();
    const float inv = 1.f / (ss[0] + ss[1] + ss[2] + ss[3]);
#pragma unroll
    for (int i = 0; i < 4; i++) {
        const int c = t + i * 256;
        if (c < 1000) out[(long)row * 1000 + c] = v[i] * inv;
    }
}

extern "C" void kernel_launch(void* const* d_in, const int* in_sizes, int n_in,
                              void* d_out, int out_size, void* d_ws, size_t ws_size,
                              hipStream_t stream)
{
    const float* x     = (const float*)d_in[0];
    const float* W_in  = (const float*)d_in[1];
    const float* b_in  = (const float*)d_in[2];
    const float* Ws[3] = {(const float*)d_in[3], (const float*)d_in[5], (const float*)d_in[7]};
    const float* bs[3] = {(const float*)d_in[4], (const float*)d_in[6], (const float*)d_in[8]};
    const float* W_out = (const float*)d_in[9];
    const float* b_out = (const float*)d_in[10];
    float* out = (float*)d_out;

    char* ws = (char*)d_ws;
    const size_t MB = 1u << 20;
    const long M1 = 1024L * 1024;        // elements per 1024x1024 bf16 matrix
    // region 0 (32 MB): xb during z0; afterwards the per-layer weight products
    bf16*  xb       = (bf16*)(ws);               // 32 MB (dead after z0)
    bf16*  Wtbf_all = (bf16*)(ws);               //  6 MB (3 x 1024^2)
    bf16*  Minv_all = (bf16*)(ws +  6 * MB);     //  6 MB
    bf16*  Bcat_all = (bf16*)(ws + 12 * MB);     // 12 MB (3 x 1024x2048)
    bf16*  Wbf_all  = (bf16*)(ws + 24 * MB);     //  6 MB
    bf16*  Winb  = (bf16*)(ws + 32 * MB);        //  4 MB
    bf16*  Wouth = (bf16*)(ws + 36 * MB);        //  2 MB
    bf16*  Woutl = (bf16*)(ws + 38 * MB);        //  2 MB
    float* u_a   = (float*)(ws + 40 * MB);       // 32 MB
    float* u_b   = (float*)(ws + 72 * MB);       // 32 MB
    bf16*  AC    = (bf16*)(ws + 104 * MB);       // 32 MB  [vr | rhsu] 8192x2048
    bf16*  vb    = (bf16*)(ws + 136 * MB);       // 16 MB  V      (total 152 MB)
    bf16*  zh    = AC;
    bf16*  zl    = AC + 8192L * 1024;
    float* logits = u_b;                         // free at l=2 (uin = u_a)

    const dim3 blk(256);
    const dim3 gBig(8, 64);
    const dim3 gSm3(8, 8, 3);
    const dim3 gT3(32, 32, 3);

    // 1-2: input conversions (xb/Winb live only until z0 completes)
    conv_xw<<<18432, blk, 0, stream>>>(x, xb, W_in, Winb);
    prep_wout<<<1024, blk, 0, stream>>>(W_out, Wouth, Woutl);

    // 3: z0 = x @ W_in^T + b_in; u_a = z0 (fp32), AC = [11*relu(z0) | z0+0.1*b1]
    gemm_bt<0><<<gBig, blk, 0, stream>>>(xb, Winb, u_a, AC, AC + 1024,
                                         nullptr, b_in, bs[0], nullptr,
                                         8192, 1024, 2048, 2048, 2048,
                                         1024, 2048, 2048, 1.f, 0, 0, 0, 0);

    // 4-6: all per-layer weight products, batched over blockIdx.z (reuse xb region)
    prep_w3<<<gT3, blk, 0, stream>>>(Ws[0], Ws[1], Ws[2], Wbf_all, Wtbf_all);
    // Minv[z] = (I - C_MSC*W^T W)/11 -> Minv_all (ld 1024) and Bcat_all[:, :1024]
    gemm_bt<1><<<gSm3, blk, 0, stream>>>(Wtbf_all, Wtbf_all, nullptr, Minv_all, Bcat_all,
                                         nullptr, nullptr, nullptr, nullptr,
                                         1024, 1024, 1024, 1024, 1024,
                                         0, 1024, 2048, 1.f, M1, M1, M1, 2 * M1);
    // Bcat_all[z][:, 1024:] = 0.1 * Minv[z] @ W[z]^T
    gemm_bt<2><<<gSm3, blk, 0, stream>>>(Minv_all, Wbf_all, nullptr, Bcat_all + 1024, nullptr,
                                         nullptr, nullptr, nullptr, nullptr,
                                         1024, 1024, 1024, 1024, 1024,
                                         0, 2048, 0, C_DT, M1, M1, 2 * M1, 0);

    // 7-12: layer loop — two big GEMMs per layer
    float* uin[3]  = {u_a, u_b, u_a};
    float* uout[3] = {u_b, u_a, nullptr};
    for (int l = 0; l < 3; l++) {
        // V = AC @ Bcat[l]^T  (K=2048)
        gemm_bt<3><<<gBig, blk, 0, stream>>>(AC, Bcat_all + l * 2 * M1, nullptr, vb, nullptr,
                                             nullptr, nullptr, nullptr, nullptr,
                                             8192, 1024, 2048, 2048, 2048,
                                             0, 1024, 0, 1.f, 0, 0, 0, 0);
        // u_out = 0.1*V@W^T - u_in - 0.1*b; epilogue builds next AC (or z split)
        if (l < 2) {
            gemm_bt<4><<<gBig, blk, 0, stream>>>(vb, Wbf_all + l * M1, uout[l], AC, AC + 1024,
                                                 uin[l], bs[l], bs[l + 1], vb,
                                                 8192, 1024, 1024, 1024, 1024,
                                                 1024, 2048, 2048, 1.f, 0, 0, 0, 0);
        } else {
            gemm_bt<5><<<gBig, blk, 0, stream>>>(vb, Wbf_all + l * M1, nullptr, zh, zl,
                                                 uin[l], bs[l], nullptr, nullptr,
                                                 8192, 1024, 1024, 1024, 1024,
                                                 1024, 1024, 1024, 1.f, 0, 0, 0, 0);
        }
    }

    // 13-14: logits (3-term split) + softmax
    gemm_split<<<gBig, blk, 0, stream>>>(zh, zl, Wouth, Woutl, logits, b_out,
                                         8192, 1024, 1024, 1000);
    softmax_rows<<<8192, blk, 0, stream>>>(logits, out);
}

// Round 6
// 526.969 us; speedup vs baseline: 1.1560x; 1.0041x over previous
//
#include <hip/hip_runtime.h>
#include <hip/hip_bf16.h>
#include <cstdint>

// I/O is FP32. Derivation: c=DT=0.1, d=1+DT/EPS=11; layer out = (-u,-v):
//   V = [vr | rhsu] @ Bcat^T, Bcat = [Minv | 0.1*(Minv W^T)] (1024x2048),
//   u_raw = 0.1 V W^T = AC @ Ccat^T, Ccat = 0.1*W@Bcat = [0.1*P | 0.01*P@W^T],
//   P = W@Minv;  un = u_raw - u_in - 0.1 b;  AC_next = [10relu(un)-V | un+0.1b'],
//   Minv = (I - (0.01/11) W^T W)/11  (Neumann, trunc err ~1.5e-6).
// R6: gemm_layer fuses V-GEMM + UMID into one dispatch (two B panels, dual
// accumulators, shared A staging) — V never touches memory. Layer 2 is a
// single u-only K=2048 GEMM. u fp32 updated in-place (same-idx read->write).

typedef __bf16 bf16;
typedef __bf16 bf16x4 __attribute__((ext_vector_type(4)));
typedef __bf16 bf16x8 __attribute__((ext_vector_type(8)));
typedef float  f32x4  __attribute__((ext_vector_type(4)));

#define C_DT    0.1f
#define C_DTEPS 10.0f
#define C_DINV  (1.0f/11.0f)
#define C_MSC   (0.01f/121.0f)

__device__ __forceinline__ void async_load16(const bf16* g, bf16* l) {
    __builtin_amdgcn_global_load_lds(
        (__attribute__((address_space(1))) void*)(g),
        (__attribute__((address_space(3))) void*)(l),
        16, 0, 0);
}

// XCD-aware remap for (8,64) grids: per-XCD L2 working set ~ row-panel + B.
__device__ __forceinline__ void remap_block(int& bx, int& by) {
    if (gridDim.y == 64) {
        const int lin  = by * 8 + bx;
        const int xcd  = lin & 7;
        const int slot = lin >> 3;
        by = xcd * 8 + (slot & 7);
        bx = slot >> 3;
    }
}

// ---------------------------------------------------------------------------
// C = A @ B^T (A: MxK ld lda, B: NxK ld ldb, bf16). 128x128 tile, BK=32,
// double-buffered, batched over blockIdx.z.
// EPI 0 Z0   : t=a+e1[n]; out_f=t; out_b1=11*relu(t); out_b2=t+0.1*e2[n]
// EPI 1 MINV : v=(m==n?1/11:0)-C_MSC*a; out_b1=v; out_b2=v
// EPI 2 SCALE: out_b1 = sgn*a; if(out_b2) out_b2 = 0.1*sgn*a
// EPI 5 ULAST: un=sgn*a-e0[m*ldf+n]-0.1*e1[n]; out_b1=hi(un); out_b2=lo(un)
// ---------------------------------------------------------------------------
template<int EPI>
__global__ __launch_bounds__(256, 2)
void gemm_bt(const bf16* __restrict__ A, const bf16* __restrict__ B,
             float* __restrict__ out_f,
             bf16* __restrict__ out_b1, bf16* __restrict__ out_b2,
             const float* __restrict__ e0, const float* __restrict__ e1,
             const float* __restrict__ e2,
             int M, int N, int K, int lda, int ldb,
             int ldf, int ld1, int ld2, float sgn,
             long zsA, long zsB, long zs1, long zs2)
{
    __shared__ __attribute__((aligned(16))) char smem[32768];
    bf16* sAe = (bf16*)smem;             // 2 x 4096 elements
    bf16* sBe = (bf16*)(smem + 16384);

    const int t    = threadIdx.x;
    const int wave = t >> 6;
    const int lane = t & 63;
    int bx = blockIdx.x, by = blockIdx.y;
    remap_block(bx, by);
    const long zb = blockIdx.z;
    A += zb * zsA;
    B += zb * zsB;
    if (out_b1) out_b1 += zb * zs1;
    if (out_b2) out_b2 += zb * zs2;

    const long row0 = (long)by * 128;
    const long col0 = (long)bx * 128;
    const int wr = wave >> 1, wc = wave & 1;

    f32x4 acc[4][4];
#pragma unroll
    for (int i = 0; i < 4; i++)
#pragma unroll
        for (int j = 0; j < 4; j++)
            acc[i][j] = f32x4{0.f, 0.f, 0.f, 0.f};

    const int  q  = t >> 2;
    const int  gp = ((t & 3) + 4 - ((q + (q >> 2)) & 3)) & 3;
    const bf16* gA = A + (row0 + q) * (long)lda + gp * 8;
    const bf16* gB = B + (col0 + q) * (long)ldb + gp * 8;

    const int l15  = lane & 15;
    const int fch  = ((lane >> 4) + l15 + (l15 >> 2)) & 3;
    const int aoff = (wr * 64 + l15) * 32 + fch * 8;
    const int boff = (wc * 64 + l15) * 32 + fch * 8;

    auto stage = [&](int buf, int k0) {
        bf16* dA = sAe + buf * 4096 + wave * 512;
        bf16* dB = sBe + buf * 4096 + wave * 512;
        async_load16(gA + k0,                     dA);
        async_load16(gA + 64 * (long)lda + k0,    dA + 2048);
        async_load16(gB + k0,                     dB);
        async_load16(gB + 64 * (long)ldb + k0,    dB + 2048);
    };

    const int nIter = K >> 5;
    stage(0, 0);
    __syncthreads();
    for (int k = 0; k < nIter; k++) {
        const int cur = k & 1;
        if (k + 1 < nIter) stage(cur ^ 1, (k + 1) << 5);

        bf16x8 af[4], bfv[4];
#pragma unroll
        for (int i = 0; i < 4; i++)
            af[i] = *(const bf16x8*)(sAe + cur * 4096 + aoff + i * 16 * 32);
#pragma unroll
        for (int j = 0; j < 4; j++)
            bfv[j] = *(const bf16x8*)(sBe + cur * 4096 + boff + j * 16 * 32);
#pragma unroll
        for (int i = 0; i < 4; i++)
#pragma unroll
            for (int j = 0; j < 4; j++)
                acc[i][j] = __builtin_amdgcn_mfma_f32_16x16x32_bf16(
                    af[i], bfv[j], acc[i][j], 0, 0, 0);

        __syncthreads();
    }

    float* epi = (float*)smem + wave * 1024;
    const int wbase = (lane >> 4) * 256 + (l15 >> 2) * 4 + (l15 & 3);

#pragma unroll
    for (int i = 0; i < 4; i++) {
#pragma unroll
        for (int j = 0; j < 4; j++)
#pragma unroll
            for (int r = 0; r < 4; r++)
                epi[wbase + r * 64 + 16 * j] = acc[i][j][r];

#pragma unroll
        for (int qq = 0; qq < 4; qq++) {
            const f32x4 a4 = ((const f32x4*)epi)[qq * 64 + lane];
            const long m = row0 + wr * 64 + i * 16 + qq * 4 + (lane >> 4);
            const long n = col0 + wc * 64 + 4 * l15;

            if (EPI == 0) {
                const f32x4 b1 = *(const f32x4*)(e1 + n);
                const f32x4 b2 = *(const f32x4*)(e2 + n);
                f32x4 tv; bf16x4 rv, hv;
#pragma unroll
                for (int e = 0; e < 4; e++) {
                    tv[e] = a4[e] + b1[e];
                    rv[e] = (bf16)(11.f * fmaxf(tv[e], 0.f));
                    hv[e] = (bf16)(tv[e] + C_DT * b2[e]);
                }
                *(f32x4*)(out_f + m * (long)ldf + n)    = tv;
                *(bf16x4*)(out_b1 + m * (long)ld1 + n)  = rv;
                *(bf16x4*)(out_b2 + m * (long)ld2 + n)  = hv;
            } else if (EPI == 1) {
                bf16x4 ov;
#pragma unroll
                for (int e = 0; e < 4; e++)
                    ov[e] = (bf16)(((m == n + e) ? C_DINV : 0.f) - C_MSC * a4[e]);
                *(bf16x4*)(out_b1 + m * (long)ld1 + n) = ov;
                *(bf16x4*)(out_b2 + m * (long)ld2 + n) = ov;
            } else if (EPI == 2) {
                bf16x4 ov, o2;
#pragma unroll
                for (int e = 0; e < 4; e++) {
                    ov[e] = (bf16)(sgn * a4[e]);
                    o2[e] = (bf16)(C_DT * sgn * a4[e]);
                }
                *(bf16x4*)(out_b1 + m * (long)ld1 + n) = ov;
                if (out_b2) *(bf16x4*)(out_b2 + m * (long)ld2 + n) = o2;
            } else {  // EPI 5
                const f32x4 u0 = *(const f32x4*)(e0 + m * (long)ldf + n);
                const f32x4 b1 = *(const f32x4*)(e1 + n);
                bf16x4 hv, lv;
#pragma unroll
                for (int e = 0; e < 4; e++) {
                    float un = sgn * a4[e] - u0[e] - C_DT * b1[e];
                    bf16 h = (bf16)un;
                    hv[e] = h;
                    lv[e] = (bf16)(un - (float)h);
                }
                *(bf16x4*)(out_b1 + m * (long)ld1 + n) = hv;
                *(bf16x4*)(out_b2 + m * (long)ld2 + n) = lv;
            }
        }
    }
}

// ---------------------------------------------------------------------------
// Fused layer: accV = AC@Bcat^T, accU = AC@Ccat^T (K=2048) in one block.
// Epilogue: un = accU - u - 0.1*bl;  u <- un (in-place);
//           ACo[:, :1024] = 10*relu(un) - accV;  ACo[:, 1024:] = un + 0.1*bn.
// ---------------------------------------------------------------------------
__global__ __launch_bounds__(256, 2)
void gemm_layer(const bf16* __restrict__ A, const bf16* __restrict__ B1,
                const bf16* __restrict__ B2, float* __restrict__ u,
                bf16* __restrict__ ACo,
                const float* __restrict__ bl, const float* __restrict__ bn)
{
    __shared__ __attribute__((aligned(16))) char smem[49152];
    bf16* sA  = (bf16*)smem;             // 2 x 4096
    bf16* sB1 = (bf16*)(smem + 16384);
    bf16* sB2 = (bf16*)(smem + 32768);

    const int t    = threadIdx.x;
    const int wave = t >> 6;
    const int lane = t & 63;
    int bx = blockIdx.x, by = blockIdx.y;
    remap_block(bx, by);
    const long row0 = (long)by * 128;
    const long col0 = (long)bx * 128;
    const int wr = wave >> 1, wc = wave & 1;

    f32x4 accU[4][4], accV[4][4];
#pragma unroll
    for (int i = 0; i < 4; i++)
#pragma unroll
        for (int j = 0; j < 4; j++) {
            accU[i][j] = f32x4{0.f, 0.f, 0.f, 0.f};
            accV[i][j] = f32x4{0.f, 0.f, 0.f, 0.f};
        }

    const int  q  = t >> 2;
    const int  gp = ((t & 3) + 4 - ((q + (q >> 2)) & 3)) & 3;
    const bf16* gA  = A  + (row0 + q) * 2048 + gp * 8;
    const bf16* gB1 = B1 + (col0 + q) * 2048 + gp * 8;
    const bf16* gB2 = B2 + (col0 + q) * 2048 + gp * 8;

    const int l15  = lane & 15;
    const int fch  = ((lane >> 4) + l15 + (l15 >> 2)) & 3;
    const int aoff = (wr * 64 + l15) * 32 + fch * 8;
    const int boff = (wc * 64 + l15) * 32 + fch * 8;

    auto stage = [&](int buf, int k0) {
        bf16* dA  = sA  + buf * 4096 + wave * 512;
        bf16* dB1 = sB1 + buf * 4096 + wave * 512;
        bf16* dB2 = sB2 + buf * 4096 + wave * 512;
        async_load16(gA  + k0,             dA);
        async_load16(gA  + 64 * 2048 + k0, dA + 2048);
        async_load16(gB1 + k0,             dB1);
        async_load16(gB1 + 64 * 2048 + k0, dB1 + 2048);
        async_load16(gB2 + k0,             dB2);
        async_load16(gB2 + 64 * 2048 + k0, dB2 + 2048);
    };

    stage(0, 0);
    __syncthreads();
    for (int k = 0; k < 64; k++) {
        const int cur = k & 1;
        if (k + 1 < 64) stage(cur ^ 1, (k + 1) << 5);

        bf16x8 af[4], b1v[4], b2v[4];
#pragma unroll
        for (int i = 0; i < 4; i++)
            af[i] = *(const bf16x8*)(sA + cur * 4096 + aoff + i * 16 * 32);
#pragma unroll
        for (int j = 0; j < 4; j++) {
            b1v[j] = *(const bf16x8*)(sB1 + cur * 4096 + boff + j * 16 * 32);
            b2v[j] = *(const bf16x8*)(sB2 + cur * 4096 + boff + j * 16 * 32);
        }
#pragma unroll
        for (int i = 0; i < 4; i++)
#pragma unroll
            for (int j = 0; j < 4; j++) {
                accV[i][j] = __builtin_amdgcn_mfma_f32_16x16x32_bf16(
                    af[i], b1v[j], accV[i][j], 0, 0, 0);
                accU[i][j] = __builtin_amdgcn_mfma_f32_16x16x32_bf16(
                    af[i], b2v[j], accU[i][j], 0, 0, 0);
            }
        __syncthreads();
    }

    float* epi = (float*)smem + wave * 1024;
    const int wbase = (lane >> 4) * 256 + (l15 >> 2) * 4 + (l15 & 3);

#pragma unroll
    for (int i = 0; i < 4; i++) {
        // V slice through LDS transpose
#pragma unroll
        for (int j = 0; j < 4; j++)
#pragma unroll
            for (int r = 0; r < 4; r++)
                epi[wbase + r * 64 + 16 * j] = accV[i][j][r];
        f32x4 v4[4];
#pragma unroll
        for (int qq = 0; qq < 4; qq++)
            v4[qq] = ((const f32x4*)epi)[qq * 64 + lane];
        // U slice (overwrites; same-wave DS ops are in-order)
#pragma unroll
        for (int j = 0; j < 4; j++)
#pragma unroll
            for (int r = 0; r < 4; r++)
                epi[wbase + r * 64 + 16 * j] = accU[i][j][r];

#pragma unroll
        for (int qq = 0; qq < 4; qq++) {
            const f32x4 a4 = ((const f32x4*)epi)[qq * 64 + lane];
            const long m  = row0 + wr * 64 + i * 16 + qq * 4 + (lane >> 4);
            const long n  = col0 + wc * 64 + 4 * l15;
            const long iu = m * 1024 + n;
            const f32x4 u0 = *(const f32x4*)(u + iu);
            const f32x4 c1 = *(const f32x4*)(bl + n);
            const f32x4 c2 = *(const f32x4*)(bn + n);
            f32x4 un; bf16x4 rv, hv;
#pragma unroll
            for (int e = 0; e < 4; e++) {
                un[e] = a4[e] - u0[e] - C_DT * c1[e];
                rv[e] = (bf16)(C_DTEPS * fmaxf(un[e], 0.f) - v4[qq][e]);
                hv[e] = (bf16)(un[e] + C_DT * c2[e]);
            }
            *(f32x4*)(u + iu) = un;
            *(bf16x4*)(ACo + m * 2048 + n)        = rv;
            *(bf16x4*)(ACo + m * 2048 + 1024 + n) = hv;
        }
    }
}

// logits = (Ah+Al)@(Bh+Bl)^T + bias (3-term), fp32 out, double-buffered.
__global__ __launch_bounds__(256, 2)
void gemm_split(const bf16* __restrict__ Ah, const bf16* __restrict__ Al,
                const bf16* __restrict__ Bh, const bf16* __restrict__ Bl,
                float* __restrict__ out, const float* __restrict__ bias,
                int M, int N, int K, int blim)
{
    __shared__ __attribute__((aligned(16))) char smem[65536];
    bf16* sAh = (bf16*)smem;
    bf16* sAl = (bf16*)(smem + 16384);
    bf16* sBh = (bf16*)(smem + 32768);
    bf16* sBl = (bf16*)(smem + 49152);

    const int t    = threadIdx.x;
    const int wave = t >> 6;
    const int lane = t & 63;
    int bx = blockIdx.x, by = blockIdx.y;
    remap_block(bx, by);
    const long row0 = (long)by * 128;
    const long col0 = (long)bx * 128;
    const int wr = wave >> 1, wc = wave & 1;

    f32x4 acc[4][4];
#pragma unroll
    for (int i = 0; i < 4; i++)
#pragma unroll
        for (int j = 0; j < 4; j++)
            acc[i][j] = f32x4{0.f, 0.f, 0.f, 0.f};

    const int  q  = t >> 2;
    const int  gp = ((t & 3) + 4 - ((q + (q >> 2)) & 3)) & 3;
    const long gao = (row0 + q) * (long)K + gp * 8;
    const long gbo = (col0 + q) * (long)K + gp * 8;

    const int l15  = lane & 15;
    const int fch  = ((lane >> 4) + l15 + (l15 >> 2)) & 3;
    const int aoff = (wr * 64 + l15) * 32 + fch * 8;
    const int boff = (wc * 64 + l15) * 32 + fch * 8;

    auto stage = [&](int buf, int k0) {
        const int d = buf * 4096 + wave * 512;
        async_load16(Ah + gao + k0,                 sAh + d);
        async_load16(Ah + gao + 64 * (long)K + k0,  sAh + d + 2048);
        async_load16(Al + gao + k0,                 sAl + d);
        async_load16(Al + gao + 64 * (long)K + k0,  sAl + d + 2048);
        async_load16(Bh + gbo + k0,                 sBh + d);
        async_load16(Bh + gbo + 64 * (long)K + k0,  sBh + d + 2048);
        async_load16(Bl + gbo + k0,                 sBl + d);
        async_load16(Bl + gbo + 64 * (long)K + k0,  sBl + d + 2048);
    };

    const int nIter = K >> 5;
    stage(0, 0);
    __syncthreads();
    for (int k = 0; k < nIter; k++) {
        const int cur = k & 1;
        if (k + 1 < nIter) stage(cur ^ 1, (k + 1) << 5);

        bf16x8 ah[4], al[4], bh[4], bl[4];
#pragma unroll
        for (int i = 0; i < 4; i++) {
            ah[i] = *(const bf16x8*)(sAh + cur * 4096 + aoff + i * 16 * 32);
            al[i] = *(const bf16x8*)(sAl + cur * 4096 + aoff + i * 16 * 32);
        }
#pragma unroll
        for (int j = 0; j < 4; j++) {
            bh[j] = *(const bf16x8*)(sBh + cur * 4096 + boff + j * 16 * 32);
            bl[j] = *(const bf16x8*)(sBl + cur * 4096 + boff + j * 16 * 32);
        }
#pragma unroll
        for (int i = 0; i < 4; i++)
#pragma unroll
            for (int j = 0; j < 4; j++) {
                acc[i][j] = __builtin_amdgcn_mfma_f32_16x16x32_bf16(
                    ah[i], bh[j], acc[i][j], 0, 0, 0);
                acc[i][j] = __builtin_amdgcn_mfma_f32_16x16x32_bf16(
                    ah[i], bl[j], acc[i][j], 0, 0, 0);
                acc[i][j] = __builtin_amdgcn_mfma_f32_16x16x32_bf16(
                    al[i], bh[j], acc[i][j], 0, 0, 0);
            }
        __syncthreads();
    }

    float* epi = (float*)smem + wave * 1024;
    const int wbase = (lane >> 4) * 256 + (l15 >> 2) * 4 + (l15 & 3);

#pragma unroll
    for (int i = 0; i < 4; i++) {
#pragma unroll
        for (int j = 0; j < 4; j++)
#pragma unroll
            for (int r = 0; r < 4; r++)
                epi[wbase + r * 64 + 16 * j] = acc[i][j][r];

#pragma unroll
        for (int qq = 0; qq < 4; qq++) {
            f32x4 a4 = ((const f32x4*)epi)[qq * 64 + lane];
            const long m = row0 + wr * 64 + i * 16 + qq * 4 + (lane >> 4);
            const long n = col0 + wc * 64 + 4 * l15;
            f32x4 bv = f32x4{0.f, 0.f, 0.f, 0.f};
            if (n < blim) bv = *(const f32x4*)(bias + n);
#pragma unroll
            for (int e = 0; e < 4; e++) a4[e] += bv[e];
            *(f32x4*)(out + m * (long)N + n) = a4;
        }
    }
}

// fp32 -> bf16 for x (16384 blocks) and W_in (2048 blocks) in one dispatch
__global__ void conv_xw(const float* __restrict__ x, bf16* __restrict__ xb,
                        const float* __restrict__ w, bf16* __restrict__ wb)
{
    const long bid = blockIdx.x;
    const float* in;
    bf16* outp;
    long i4;
    if (bid < 16384) { in = x; outp = xb; i4 = bid * 256 + threadIdx.x; }
    else             { in = w; outp = wb; i4 = (bid - 16384) * 256 + threadIdx.x; }
    const f32x4 v = ((const f32x4*)in)[i4];
    bf16x4 o;
#pragma unroll
    for (int e = 0; e < 4; e++) o[e] = (bf16)v[e];
    ((bf16x4*)outp)[i4] = o;
}

// Batched: W[z] (1024x1024 fp32) -> Wb[z] bf16, Wtb[z] = bf16(W^T)
__global__ void prep_w3(const float* __restrict__ w0, const float* __restrict__ w1,
                        const float* __restrict__ w2, bf16* __restrict__ Wb,
                        bf16* __restrict__ Wtb)
{
    __shared__ float tile[32][33];
    const int z = blockIdx.z;
    const float* W = (z == 0) ? w0 : (z == 1) ? w1 : w2;
    const long zo = (long)z * 1024 * 1024;
    const int bx = blockIdx.x * 32, by = blockIdx.y * 32;
    const int tx = threadIdx.x & 31, ty = threadIdx.x >> 5;
#pragma unroll
    for (int i = 0; i < 32; i += 8) {
        float v = W[(long)(by + ty + i) * 1024 + bx + tx];
        tile[ty + i][tx] = v;
        Wb[zo + (long)(by + ty + i) * 1024 + bx + tx] = (bf16)v;
    }
    __syncthreads();
#pragma unroll
    for (int i = 0; i < 32; i += 8)
        Wtb[zo + (long)(bx + ty + i) * 1024 + by + tx] = (bf16)tile[tx][ty + i];
}

__global__ void prep_wout(const float* __restrict__ w, bf16* __restrict__ wh,
                          bf16* __restrict__ wl)
{
    const long i4   = (long)blockIdx.x * 256 + threadIdx.x;
    const long base = i4 * 4;
    const int  nrow = (int)(base >> 10);
    bf16x4 h, l;
    if (nrow < 1000) {
        const f32x4 v = ((const f32x4*)w)[i4];
#pragma unroll
        for (int e = 0; e < 4; e++) {
            bf16 hh = (bf16)v[e];
            h[e] = hh;
            l[e] = (bf16)(v[e] - (float)hh);
        }
    } else {
#pragma unroll
        for (int e = 0; e < 4; e++) { h[e] = (bf16)0.f; l[e] = (bf16)0.f; }
    }
    ((bf16x4*)wh)[i4] = h;
    ((bf16x4*)wl)[i4] = l;
}

__global__ __launch_bounds__(256)
void softmax_rows(const float* __restrict__ logits, float* __restrict__ out)
{
    const int row = blockIdx.x;
    const float* lp = logits + (long)row * 1024;
    const int t = threadIdx.x;
    float v[4];
    float mx = -1e30f;
#pragma unroll
    for (int i = 0; i < 4; i++) {
        const int c = t + i * 256;
        v[i] = (c < 1000) ? lp[c] : -1e30f;
        mx = fmaxf(mx, v[i]);
    }
#pragma unroll
    for (int off = 32; off; off >>= 1)
        mx = fmaxf(mx, __shfl_xor(mx, off));
    __shared__ float sm[4], ss[4];
    const int wave = t >> 6;
    if ((t & 63) == 0) sm[wave] = mx;
    __syncthreads();
    mx = fmaxf(fmaxf(sm[0], sm[1]), fmaxf(sm[2], sm[3]));
    float sum = 0.f;
#pragma unroll
    for (int i = 0; i < 4; i++) {
        v[i] = __expf(v[i] - mx);
        sum += v[i];
    }
#pragma unroll
    for (int off = 32; off; off >>= 1)
        sum += __shfl_xor(sum, off);
    if ((t & 63) == 0) ss[wave] = sum;
    __syncthreads();
    const float inv = 1.f / (ss[0] + ss[1] + ss[2] + ss[3]);
#pragma unroll
    for (int i = 0; i < 4; i++) {
        const int c = t + i * 256;
        if (c < 1000) out[(long)row * 1000 + c] = v[i] * inv;
    }
}

extern "C" void kernel_launch(void* const* d_in, const int* in_sizes, int n_in,
                              void* d_out, int out_size, void* d_ws, size_t ws_size,
                              hipStream_t stream)
{
    const float* x     = (const float*)d_in[0];
    const float* W_in  = (const float*)d_in[1];
    const float* b_in  = (const float*)d_in[2];
    const float* Ws[3] = {(const float*)d_in[3], (const float*)d_in[5], (const float*)d_in[7]};
    const float* bs[3] = {(const float*)d_in[4], (const float*)d_in[6], (const float*)d_in[8]};
    const float* W_out = (const float*)d_in[9];
    const float* b_out = (const float*)d_in[10];
    float* out = (float*)d_out;

    char* ws = (char*)d_ws;
    const size_t MB = 1u << 20;
    const long M1 = 1024L * 1024;
    // 0..32MB: xb (z0) -> {Wtbf@0, Minv@6, P@12, Bcat@18..30} -> zh/zl (L2 out)
    bf16*  xb    = (bf16*)(ws);
    bf16*  Wtbf  = (bf16*)(ws);
    bf16*  Minv  = (bf16*)(ws +  6 * MB);
    bf16*  Pmat  = (bf16*)(ws + 12 * MB);
    bf16*  Bcat  = (bf16*)(ws + 18 * MB);   // 3 x 1024x2048
    bf16*  zh    = (bf16*)(ws);             // 16 MB
    bf16*  zl    = (bf16*)(ws + 16 * MB);   // 16 MB
    bf16*  Winb  = (bf16*)(ws + 32 * MB);   //  4 MB
    bf16*  Wouth = (bf16*)(ws + 36 * MB);   //  2 MB
    bf16*  Woutl = (bf16*)(ws + 38 * MB);   //  2 MB
    bf16*  Wbf   = (bf16*)(ws + 40 * MB);   //  6 MB
    bf16*  Ccat  = (bf16*)(ws + 46 * MB);   // 12 MB (3 x 1024x2048)
    float* u     = (float*)(ws + 58 * MB);  // 32 MB (in-place) -> logits
    float* logits= (float*)(ws + 58 * MB);
    bf16*  AC_a  = (bf16*)(ws + 90 * MB);   // 32 MB
    bf16*  AC_b  = (bf16*)(ws + 122 * MB);  // 32 MB (peak 154 MB)

    const dim3 blk(256);
    const dim3 gBig(8, 64);
    const dim3 gSm3(8, 8, 3);
    const dim3 gT3(32, 32, 3);

    // 1-2: conversions
    conv_xw<<<18432, blk, 0, stream>>>(x, xb, W_in, Winb);
    prep_wout<<<1024, blk, 0, stream>>>(W_out, Wouth, Woutl);

    // 3: z0 = x@W_in^T + b_in; u=z0 (fp32), AC_a=[11relu(z0) | z0+0.1*b1]
    gemm_bt<0><<<gBig, blk, 0, stream>>>(xb, Winb, u, AC_a, AC_a + 1024,
                                         nullptr, b_in, bs[0],
                                         8192, 1024, 2048, 2048, 2048,
                                         1024, 2048, 2048, 1.f, 0, 0, 0, 0);

    // 4: weight transposes (xb region is dead now)
    prep_w3<<<gT3, blk, 0, stream>>>(Ws[0], Ws[1], Ws[2], Wbf, Wtbf);
    // 5: Minv[z] -> Minv (ld1024) and Bcat[:, :1024] (ld2048)
    gemm_bt<1><<<gSm3, blk, 0, stream>>>(Wtbf, Wtbf, nullptr, Minv, Bcat,
                                         nullptr, nullptr, nullptr,
                                         1024, 1024, 1024, 1024, 1024,
                                         0, 1024, 2048, 1.f, M1, M1, M1, 2 * M1);
    // 6: Bcat[:, 1024:] = 0.1 * Minv @ W^T
    gemm_bt<2><<<gSm3, blk, 0, stream>>>(Minv, Wbf, nullptr, Bcat + 1024, nullptr,
                                         nullptr, nullptr, nullptr,
                                         1024, 1024, 1024, 1024, 1024,
                                         0, 2048, 0, C_DT, M1, M1, 2 * M1, 0);
    // 7: P = W @ Minv (Minv symmetric); also Ccat[:, :1024] = 0.1*P
    gemm_bt<2><<<gSm3, blk, 0, stream>>>(Wbf, Minv, nullptr, Pmat, Ccat,
                                         nullptr, nullptr, nullptr,
                                         1024, 1024, 1024, 1024, 1024,
                                         0, 1024, 2048, 1.f, M1, M1, M1, 2 * M1);
    // 8: Ccat[:, 1024:] = 0.01 * P @ W^T
    gemm_bt<2><<<gSm3, blk, 0, stream>>>(Pmat, Wbf, nullptr, Ccat + 1024, nullptr,
                                         nullptr, nullptr, nullptr,
                                         1024, 1024, 1024, 1024, 1024,
                                         0, 2048, 0, 0.01f, M1, M1, 2 * M1, 0);

    // 9-10: fused layers 0,1 (V in registers only)
    gemm_layer<<<gBig, blk, 0, stream>>>(AC_a, Bcat, Ccat, u, AC_b, bs[0], bs[1]);
    gemm_layer<<<gBig, blk, 0, stream>>>(AC_b, Bcat + 2 * M1, Ccat + 2 * M1,
                                         u, AC_a, bs[1], bs[2]);
    // 11: layer 2 u-only: z = AC_a @ Ccat2^T - u - 0.1*b3 -> zh/zl
    gemm_bt<5><<<gBig, blk, 0, stream>>>(AC_a, Ccat + 4 * M1, nullptr, zh, zl,
                                         u, bs[2], nullptr,
                                         8192, 1024, 2048, 2048, 2048,
                                         1024, 1024, 1024, 1.f, 0, 0, 0, 0);

    // 12-13: logits (3-term split) + softmax
    gemm_split<<<gBig, blk, 0, stream>>>(zh, zl, Wouth, Woutl, logits, b_out,
                                         8192, 1024, 1024, 1000);
    softmax_rows<<<8192, blk, 0, stream>>>(logits, out);
}